// Round 8
// baseline (330.844 us; speedup 1.0000x reference)
//
#include <hip/hip_runtime.h>
#include <cstddef>
#include <cstdint>

// ---------------------------------------------------------------------------
// MultiHeadRelativeAttention (music-transformer skew), B=4 H=16 S=1024 hd=64
// Inputs/outputs f32; internal bf16 MFMA.
// R8: attn restructured into 256-k super-iterations: one band build + 4
// independent score chains + one deep PV GEMM per super-iter; row-sums via
// all-ones MFMA (shuffle reduce deleted). GEMMs unchanged from R7.
// ws (bf16 elems, EM=1M): WT[0,3EM) relb[3,4EM) Kp[4,8EM) Vt[8,12EM) = 24 MB.
// Post-attn: WoT over WT, att copy over Kp.
// d_out scratch: Qp bf16 [0,4M elems), attb bf16 [4M,8M); final GEMM f32.
// ---------------------------------------------------------------------------

typedef __attribute__((ext_vector_type(8))) short bf16x8;   // 8 bf16, 4 VGPRs
typedef __attribute__((ext_vector_type(4))) float f32x4;
typedef __attribute__((ext_vector_type(4))) unsigned int u32x4;

using u16 = unsigned short;
using u32 = unsigned int;

__device__ __forceinline__ f32x4 mfma16(bf16x8 a, bf16x8 b, f32x4 c) {
  return __builtin_amdgcn_mfma_f32_16x16x32_bf16(a, b, c, 0, 0, 0);
}
__device__ __forceinline__ u32 fbits(float f) {
  union { float f; u32 u; } v; v.f = f; return v.u;
}
// f32 -> bf16, round-half-up (tie bias negligible at this threshold)
__device__ __forceinline__ u16 f2b(float f) { return (u16)((fbits(f) + 0x8000u) >> 16); }
__device__ __forceinline__ u32 pack2(float a, float b) {
  return ((fbits(a) + 0x8000u) >> 16) | ((fbits(b) + 0x8000u) & 0xffff0000u);
}
__device__ __forceinline__ float b2f(u16 u) {
  union { u32 i; float f; } v; v.i = ((u32)u) << 16; return v.f;
}

// ---- prep: z=0..2 transpose Wq/Wk/Wv (f32 -> bf16^T, Wq pre-scaled by 1/8);
//      z=3 convert rel_tab f32 -> bf16 ---------------------------------------
__global__ __launch_bounds__(256) void prep(
    const float* __restrict__ Wq, const float* __restrict__ Wk,
    const float* __restrict__ Wv, const float* __restrict__ rel,
    u16* __restrict__ WqT, u16* __restrict__ WkT, u16* __restrict__ WvT,
    u16* __restrict__ relb) {
  __shared__ __align__(16) u16 tile[64][65];
  int z = blockIdx.z;
  if (z == 3) {
    int blk = blockIdx.y * 16 + blockIdx.x;
    size_t base = (size_t)blk * 4096;
#pragma unroll
    for (int e = 0; e < 4; e++) {
      size_t idx = base + e * 1024 + threadIdx.x * 4;
      f32x4 v = *(const f32x4*)(rel + idx);
      uint2 pk; pk.x = pack2(v[0], v[1]); pk.y = pack2(v[2], v[3]);
      *(uint2*)(relb + idx) = pk;
    }
    return;
  }
  const float* W = (z == 0) ? Wq : (z == 1) ? Wk : Wv;
  u16* T = (z == 0) ? WqT : (z == 1) ? WkT : WvT;
  float sc = (z == 0) ? 0.125f : 1.0f;   // fold attention scale into Wq
  int k0 = blockIdx.x * 64, n0 = blockIdx.y * 64;
  for (int e = threadIdx.x; e < 4096; e += 256) {
    int r = e >> 6, c = e & 63;
    tile[r][c] = f2b(sc * W[(size_t)(k0 + r) * 1024 + n0 + c]);
  }
  __syncthreads();
  for (int e = threadIdx.x; e < 4096; e += 256) {
    int r = e >> 6, c = e & 63;
    T[(size_t)(n0 + r) * 1024 + k0 + c] = tile[c][r];
  }
}

// ---- transpose Wo (f32 -> bf16^T), after attn, into dead WT region ---------
__global__ __launch_bounds__(256) void transpose_wo(
    const float* __restrict__ W, u16* __restrict__ T) {
  __shared__ __align__(16) u16 tile[64][65];
  int k0 = blockIdx.x * 64, n0 = blockIdx.y * 64;
  for (int e = threadIdx.x; e < 4096; e += 256) {
    int r = e >> 6, c = e & 63;
    tile[r][c] = f2b(W[(size_t)(k0 + r) * 1024 + n0 + c]);
  }
  __syncthreads();
  for (int e = threadIdx.x; e < 4096; e += 256) {
    int r = e >> 6, c = e & 63;
    T[(size_t)(n0 + r) * 1024 + k0 + c] = tile[c][r];
  }
}

// ---- 128x128x(BK=64) LDS-staged GEMM: C = A @ Bt^T + bscale*bias ----------
template <bool AF32>
__device__ __forceinline__ void gemm128_body(
    const void* __restrict__ Av, const u16* __restrict__ Bt,
    const float* __restrict__ bias, float bscale, void* __restrict__ Cv,
    int layout) {
  __shared__ __align__(16) u16 As[128][72];
  __shared__ __align__(16) u16 Bs[128][72];
  int m0 = blockIdx.x * 128, n0 = blockIdx.y * 128;
  int tid = threadIdx.x;
  int w = tid >> 6, lane = tid & 63, quad = lane >> 4, ln = lane & 15;
  int wr = (w >> 1) * 64, wc = (w & 1) * 64;     // wave quadrant origin
  int sr = tid >> 1, seg = (tid & 1) * 32;       // staging: row, 32-col segment

  f32x4 acc[4][4];
#pragma unroll
  for (int i = 0; i < 4; i++)
#pragma unroll
    for (int j = 0; j < 4; j++) { acc[i][j][0]=0.f; acc[i][j][1]=0.f; acc[i][j][2]=0.f; acc[i][j][3]=0.f; }

  for (int k0 = 0; k0 < 1024; k0 += 64) {
    if (AF32) {
      const float* ap = (const float*)Av + (size_t)(m0 + sr) * 1024 + k0 + seg;
      u32 pk[16];
#pragma unroll
      for (int j = 0; j < 8; j++) {
        f32x4 v = *(const f32x4*)(ap + 4 * j);
        pk[2 * j]     = pack2(v[0], v[1]);
        pk[2 * j + 1] = pack2(v[2], v[3]);
      }
      u32* d = (u32*)&As[sr][seg];
#pragma unroll
      for (int j = 0; j < 4; j++) *(u32x4*)(d + 4 * j) = *(u32x4*)(pk + 4 * j);
    } else {
      const u16* ap = (const u16*)Av + (size_t)(m0 + sr) * 1024 + k0 + seg;
#pragma unroll
      for (int j = 0; j < 4; j++)
        *(bf16x8*)&As[sr][seg + 8 * j] = *(const bf16x8*)(ap + 8 * j);
    }
    {
      const u16* bp = Bt + (size_t)(n0 + sr) * 1024 + k0 + seg;
#pragma unroll
      for (int j = 0; j < 4; j++)
        *(bf16x8*)&Bs[sr][seg + 8 * j] = *(const bf16x8*)(bp + 8 * j);
    }
    __syncthreads();
#pragma unroll
    for (int kk = 0; kk < 64; kk += 32) {
      bf16x8 af[4], bfr[4];
#pragma unroll
      for (int rt = 0; rt < 4; rt++)
        af[rt] = *(const bf16x8*)&As[wr + 16 * rt + ln][kk + quad * 8];
#pragma unroll
      for (int ct = 0; ct < 4; ct++)
        bfr[ct] = *(const bf16x8*)&Bs[wc + 16 * ct + ln][kk + quad * 8];
#pragma unroll
      for (int rt = 0; rt < 4; rt++)
#pragma unroll
        for (int ct = 0; ct < 4; ct++)
          acc[rt][ct] = mfma16(af[rt], bfr[ct], acc[rt][ct]);
    }
    __syncthreads();
  }

#pragma unroll
  for (int ct = 0; ct < 4; ct++) {
    int n = n0 + wc + 16 * ct + ln;
    float bs = bscale * bias[n];
#pragma unroll
    for (int rt = 0; rt < 4; rt++) {
#pragma unroll
      for (int r = 0; r < 4; r++) {
        int m = m0 + wr + 16 * rt + quad * 4 + r;
        float v = acc[rt][ct][r] + bs;
        if (layout == 0) {
          ((float*)Cv)[(size_t)m * 1024 + n] = v;
        } else {
          int b_ = m >> 10, s = m & 1023, h = n >> 6, d = n & 63;
          size_t idx = (layout == 1)
              ? ((size_t)(b_ * 16 + h) * 1024 + s) * 64 + d
              : ((size_t)(b_ * 16 + h) * 64 + d) * 1024 + s;
          ((u16*)Cv)[idx] = f2b(v);
        }
      }
    }
  }
}

__global__ __launch_bounds__(256) void gemm_qkv(
    const float* q, const float* k, const float* v, const u16* WT,
    const float* bq, const float* bk, const float* bv,
    u16* Qp, u16* Kp, u16* Vt) {
  int z = blockIdx.z;
  const void* A = (z == 0) ? (const void*)q : (z == 1) ? (const void*)k : (const void*)v;
  const u16* Bt = WT + (size_t)z * (1024 * 1024);
  const float* bias = (z == 0) ? bq : (z == 1) ? bk : bv;
  float bscale = (z == 0) ? 0.125f : 1.0f;
  void* C = (z == 0) ? (void*)Qp : (z == 1) ? (void*)Kp : (void*)Vt;
  gemm128_body<true>(A, Bt, bias, bscale, C, (z == 2) ? 2 : 1);
}

__global__ __launch_bounds__(256) void gemm_out(
    const u16* A, const u16* Bt, const float* bias, float* C) {
  gemm128_body<false>(A, Bt, bias, 1.0f, C, 0);
}

// ---- flash causal attention, 256-k super-iterations ------------------------
// Q (pre-scaled 1/8), K: [bh][s][64] bf16; Vt: [bh][64][s] bf16; RB bf16.
// Per super-iter: build 320-row rel band (direct-offset slots) -> 4
// independent score-tile chains (QK MFMA + gather + exp -> P in LDS) -> one
// PV GEMM over 256 k. Row sums l via all-ones-B MFMA (lands in O's lanes).
// All LDS stripes wave-private -> no barriers, only s_waitcnt lgkmcnt(0).
#define BSTRIDE 332   // u16 row stride; quads land in distinct 8-bank windows
#define PSTRIDE 280   // u16 row stride; rows 16B-aligned for ds_read_b128

__global__ __launch_bounds__(256) void attn_v2(
    const u16* __restrict__ Q, const u16* __restrict__ K,
    const u16* __restrict__ Vt, const u16* __restrict__ RB,
    u16* __restrict__ att) {
  __shared__ __align__(16) u16 lPR[64 * BSTRIDE];  // rel band, 320 slots used
  __shared__ __align__(16) u16 lP[64 * PSTRIDE];   // P tile, 256 cols used

  int bh = blockIdx.x;
  int qt = 15 - blockIdx.y;                        // heavy tiles first
  int b = bh >> 4, h = bh & 15;
  int tid = threadIdx.x;
  int w = tid >> 6, lane = tid & 63, quad = lane >> 4, ln = lane & 15;

  const u16* Qb = Q + (size_t)bh * 65536;
  const u16* Kb = K + (size_t)bh * 65536;
  const u16* Vb = Vt + (size_t)bh * 65536;
  const u16* Rb = RB + h * 64;                     // row stride 1024

  int row0 = 16 * w + quad * 4;                    // C-layout row base
  int i0 = qt * 64;
  int R0f = 960 - i0;

  int qrow = i0 + 16 * w + ln;
  bf16x8 qa0 = *(const bf16x8*)(Qb + (size_t)qrow * 64 + quad * 8);
  bf16x8 qa1 = *(const bf16x8*)(Qb + (size_t)qrow * 64 + 32 + quad * 8);

  bf16x8 ones;
#pragma unroll
  for (int i = 0; i < 8; i++) ones[i] = (short)0x3F80;  // bf16 1.0

  f32x4 o[4], lacc;
#pragma unroll
  for (int c = 0; c < 4; c++) { o[c][0]=0.f; o[c][1]=0.f; o[c][2]=0.f; o[c][3]=0.f; }
  lacc[0]=0.f; lacc[1]=0.f; lacc[2]=0.f; lacc[3]=0.f;

#pragma unroll 1
  for (int js = 0; js <= i0; js += 256) {
    int ntiles = ((i0 - js) >> 6) + 1;
    if (ntiles > 4) ntiles = 4;
    int base = R0f + js;

    // ---- rel band: rows [base, base + 64*(ntiles+1)) ----
    int G = 4 * (ntiles + 1);
#pragma unroll 1
    for (int g = 0; g < G; g++) {
      int rrow = base + 16 * g + ln;
      int rl = rrow > 1023 ? 1023 : rrow;          // OOB rows only hit masked cols
      const u16* Rrow = Rb + (size_t)rl * 1024 + quad * 8;
      f32x4 a; a[0]=0.f; a[1]=0.f; a[2]=0.f; a[3]=0.f;
      a = mfma16(qa0, *(const bf16x8*)(Rrow), a);
      a = mfma16(qa1, *(const bf16x8*)(Rrow + 32), a);
#pragma unroll
      for (int r = 0; r < 4; r++)
        lPR[(row0 + r) * BSTRIDE + 16 * g + ln] = f2b(a[r]);
    }
    asm volatile("s_waitcnt lgkmcnt(0)" ::: "memory");  // band visible

    // ---- 4 independent score-tile chains ----
#pragma unroll
    for (int t = 0; t < 4; t++) {
      if (t < ntiles) {
        int j0 = js + 64 * t;
        bf16x8 kf[4][2];
#pragma unroll
        for (int c = 0; c < 4; c++) {
          const u16* Krow = Kb + (size_t)(j0 + 16 * c + ln) * 64 + quad * 8;
          kf[c][0] = *(const bf16x8*)(Krow);
          kf[c][1] = *(const bf16x8*)(Krow + 32);
        }
        f32x4 sc[4];
#pragma unroll
        for (int c = 0; c < 4; c++) {
          f32x4 a; a[0]=0.f; a[1]=0.f; a[2]=0.f; a[3]=0.f;
          a = mfma16(qa0, kf[c][0], a);
          a = mfma16(qa1, kf[c][1], a);
          sc[c] = a;
        }
        bool diag = (j0 == i0);
        int cbs = 64 * t + 63;                     // band slot = cbs - ii + jj
#pragma unroll
        for (int r = 0; r < 4; r++) {
          int ii = row0 + r;
#pragma unroll
          for (int c = 0; c < 4; c++) {
            int jj = 16 * c + ln;
            float s = sc[c][r] + b2f(lPR[ii * BSTRIDE + cbs - ii + jj]);
            float p = (diag && jj > ii) ? 0.f : __expf(s);
            lP[ii * PSTRIDE + 64 * t + 16 * c + ln] = f2b(p);
          }
        }
      }
    }
    asm volatile("s_waitcnt lgkmcnt(0)" ::: "memory");  // P visible

    // ---- PV GEMM over 256 k (+ row sums via ones-B MFMA) ----
    int KC = 2 * ntiles;
#pragma unroll 1
    for (int kc = 0; kc < KC; kc++) {
      bf16x8 pa = *(const bf16x8*)&lP[(16 * w + ln) * PSTRIDE + 32 * kc + quad * 8];
      lacc = mfma16(pa, ones, lacc);
#pragma unroll
      for (int c = 0; c < 4; c++) {
        const u16* Vrow = Vb + (size_t)(16 * c + ln) * 1024 + js + 32 * kc + quad * 8;
        o[c] = mfma16(pa, *(const bf16x8*)(Vrow), o[c]);
      }
    }
    asm volatile("s_waitcnt lgkmcnt(0)" ::: "memory");  // WAR: reads done
  }

  // ---- epilogue: normalize, merge heads ----
#pragma unroll
  for (int c = 0; c < 4; c++) {
#pragma unroll
    for (int r = 0; r < 4; r++) {
      int i_abs = i0 + row0 + r;
      att[((size_t)(b * 1024 + i_abs)) * 1024 + h * 64 + 16 * c + ln] =
          f2b(o[c][r] / lacc[r]);
    }
  }
}

// ---------------------------------------------------------------------------
extern "C" void kernel_launch(void* const* d_in, const int* in_sizes, int n_in,
                              void* d_out, int out_size, void* d_ws, size_t ws_size,
                              hipStream_t stream) {
  const float* query = (const float*)d_in[0];
  const float* key   = (const float*)d_in[1];
  const float* value = (const float*)d_in[2];
  // d_in[3] = attention_mask (int32, triu k=1) -- causal, hardcoded in attn
  const float* Wq = (const float*)d_in[4];
  const float* bq = (const float*)d_in[5];
  const float* Wk = (const float*)d_in[6];
  const float* bk = (const float*)d_in[7];
  const float* Wv = (const float*)d_in[8];
  const float* bv = (const float*)d_in[9];
  const float* RT = (const float*)d_in[10];
  const float* Wo = (const float*)d_in[11];
  const float* bo = (const float*)d_in[12];
  float* out = (float*)d_out;

  const size_t EM = 1024 * 1024;     // elems of one 1024x1024 matrix
  u16* ws   = (u16*)d_ws;
  u16* WT   = ws;                    // [0,3EM): WqT, WkT, WvT
  u16* relb = ws + 3 * EM;           // [3EM,4EM)
  u16* Kp   = ws + 4 * EM;           // [4EM,8EM)
  u16* Vtp  = ws + 8 * EM;           // [8EM,12EM)   (24 MB total)
  u16* Qp   = (u16*)d_out;           // d_out scratch, front half
  u16* attb = (u16*)d_out + 4 * EM;  // d_out scratch, back half
  u16* attc = ws + 4 * EM;           // att copy over dead Kp
  u16* WoT  = ws;                    // over dead WT

  prep<<<dim3(16, 16, 4), 256, 0, stream>>>(Wq, Wk, Wv, RT,
                                            WT, WT + EM, WT + 2 * EM, relb);
  gemm_qkv<<<dim3(32, 8, 3), 256, 0, stream>>>(query, key, value, WT,
                                               bq, bk, bv, Qp, Kp, Vtp);
  attn_v2<<<dim3(64, 16), 256, 0, stream>>>(Qp, Kp, Vtp, relb, attb);
  hipMemcpyAsync(attc, attb, 8 * 1024 * 1024, hipMemcpyDeviceToDevice, stream);
  transpose_wo<<<dim3(16, 16), 256, 0, stream>>>(Wo, WoT);
  gemm_out<<<dim3(32, 8), 256, 0, stream>>>(attc, WoT, bo, out);
}

// Round 9
// 320.384 us; speedup vs baseline: 1.0326x; 1.0326x over previous
//
#include <hip/hip_runtime.h>
#include <cstddef>
#include <cstdint>

// ---------------------------------------------------------------------------
// MultiHeadRelativeAttention (music-transformer skew), B=4 H=16 S=1024 hd=64
// Inputs/outputs f32; internal bf16 MFMA.
// R9: pre-convert q/k/v f32->bf16 once (if ws >= 48MB), so the QKV GEMMs
// stage bf16 A (half traffic, no pack in hot loop). Fallback = exact R8.
// Fast ws layout (u16 elems, EM=1M): WT[0,3) relb[3,4) Kp[4,8) Vt[8,12)
//   qb[12,16) kb[16,20) vb[20,24) = 48 MB. Post-attn: WoT over WT, attc over Kp.
// d_out scratch: Qp bf16 [0,4M elems), attb bf16 [4M,8M); final GEMM f32.
// ---------------------------------------------------------------------------

typedef __attribute__((ext_vector_type(8))) short bf16x8;   // 8 bf16, 4 VGPRs
typedef __attribute__((ext_vector_type(4))) float f32x4;
typedef __attribute__((ext_vector_type(4))) unsigned int u32x4;

using u16 = unsigned short;
using u32 = unsigned int;

__device__ __forceinline__ f32x4 mfma16(bf16x8 a, bf16x8 b, f32x4 c) {
  return __builtin_amdgcn_mfma_f32_16x16x32_bf16(a, b, c, 0, 0, 0);
}
__device__ __forceinline__ u32 fbits(float f) {
  union { float f; u32 u; } v; v.f = f; return v.u;
}
// f32 -> bf16, round-half-up (tie bias negligible at this threshold)
__device__ __forceinline__ u16 f2b(float f) { return (u16)((fbits(f) + 0x8000u) >> 16); }
__device__ __forceinline__ u32 pack2(float a, float b) {
  return ((fbits(a) + 0x8000u) >> 16) | ((fbits(b) + 0x8000u) & 0xffff0000u);
}
__device__ __forceinline__ float b2f(u16 u) {
  union { u32 i; float f; } v; v.i = ((u32)u) << 16; return v.f;
}

// ---- bulk f32 -> bf16 conversion of q,k,v ----------------------------------
__global__ __launch_bounds__(256) void cvt_qkv(
    const float* __restrict__ a0, const float* __restrict__ a1,
    const float* __restrict__ a2, u16* __restrict__ o0,
    u16* __restrict__ o1, u16* __restrict__ o2) {
  int z = blockIdx.y;
  const float* src = (z == 0) ? a0 : (z == 1) ? a1 : a2;
  u16* dst = (z == 0) ? o0 : (z == 1) ? o1 : o2;
  size_t i = ((size_t)blockIdx.x * 256 + threadIdx.x) * 4;
  f32x4 v = *(const f32x4*)(src + i);
  uint2 pk; pk.x = pack2(v[0], v[1]); pk.y = pack2(v[2], v[3]);
  *(uint2*)(dst + i) = pk;
}

// ---- prep: z=0..2 transpose Wq/Wk/Wv (f32 -> bf16^T, Wq pre-scaled by 1/8);
//      z=3 convert rel_tab f32 -> bf16 ---------------------------------------
__global__ __launch_bounds__(256) void prep(
    const float* __restrict__ Wq, const float* __restrict__ Wk,
    const float* __restrict__ Wv, const float* __restrict__ rel,
    u16* __restrict__ WqT, u16* __restrict__ WkT, u16* __restrict__ WvT,
    u16* __restrict__ relb) {
  __shared__ __align__(16) u16 tile[64][65];
  int z = blockIdx.z;
  if (z == 3) {
    int blk = blockIdx.y * 16 + blockIdx.x;
    size_t base = (size_t)blk * 4096;
#pragma unroll
    for (int e = 0; e < 4; e++) {
      size_t idx = base + e * 1024 + threadIdx.x * 4;
      f32x4 v = *(const f32x4*)(rel + idx);
      uint2 pk; pk.x = pack2(v[0], v[1]); pk.y = pack2(v[2], v[3]);
      *(uint2*)(relb + idx) = pk;
    }
    return;
  }
  const float* W = (z == 0) ? Wq : (z == 1) ? Wk : Wv;
  u16* T = (z == 0) ? WqT : (z == 1) ? WkT : WvT;
  float sc = (z == 0) ? 0.125f : 1.0f;   // fold attention scale into Wq
  int k0 = blockIdx.x * 64, n0 = blockIdx.y * 64;
  for (int e = threadIdx.x; e < 4096; e += 256) {
    int r = e >> 6, c = e & 63;
    tile[r][c] = f2b(sc * W[(size_t)(k0 + r) * 1024 + n0 + c]);
  }
  __syncthreads();
  for (int e = threadIdx.x; e < 4096; e += 256) {
    int r = e >> 6, c = e & 63;
    T[(size_t)(n0 + r) * 1024 + k0 + c] = tile[c][r];
  }
}

// ---- transpose Wo (f32 -> bf16^T), after attn, into dead WT region ---------
__global__ __launch_bounds__(256) void transpose_wo(
    const float* __restrict__ W, u16* __restrict__ T) {
  __shared__ __align__(16) u16 tile[64][65];
  int k0 = blockIdx.x * 64, n0 = blockIdx.y * 64;
  for (int e = threadIdx.x; e < 4096; e += 256) {
    int r = e >> 6, c = e & 63;
    tile[r][c] = f2b(W[(size_t)(k0 + r) * 1024 + n0 + c]);
  }
  __syncthreads();
  for (int e = threadIdx.x; e < 4096; e += 256) {
    int r = e >> 6, c = e & 63;
    T[(size_t)(n0 + r) * 1024 + k0 + c] = tile[c][r];
  }
}

// ---- 128x128x(BK=64) LDS-staged GEMM: C = A @ Bt^T + bscale*bias ----------
template <bool AF32>
__device__ __forceinline__ void gemm128_body(
    const void* __restrict__ Av, const u16* __restrict__ Bt,
    const float* __restrict__ bias, float bscale, void* __restrict__ Cv,
    int layout) {
  __shared__ __align__(16) u16 As[128][72];
  __shared__ __align__(16) u16 Bs[128][72];
  int m0 = blockIdx.x * 128, n0 = blockIdx.y * 128;
  int tid = threadIdx.x;
  int w = tid >> 6, lane = tid & 63, quad = lane >> 4, ln = lane & 15;
  int wr = (w >> 1) * 64, wc = (w & 1) * 64;     // wave quadrant origin
  int sr = tid >> 1, seg = (tid & 1) * 32;       // staging: row, 32-col segment

  f32x4 acc[4][4];
#pragma unroll
  for (int i = 0; i < 4; i++)
#pragma unroll
    for (int j = 0; j < 4; j++) { acc[i][j][0]=0.f; acc[i][j][1]=0.f; acc[i][j][2]=0.f; acc[i][j][3]=0.f; }

  for (int k0 = 0; k0 < 1024; k0 += 64) {
    if (AF32) {
      const float* ap = (const float*)Av + (size_t)(m0 + sr) * 1024 + k0 + seg;
      u32 pk[16];
#pragma unroll
      for (int j = 0; j < 8; j++) {
        f32x4 v = *(const f32x4*)(ap + 4 * j);
        pk[2 * j]     = pack2(v[0], v[1]);
        pk[2 * j + 1] = pack2(v[2], v[3]);
      }
      u32* d = (u32*)&As[sr][seg];
#pragma unroll
      for (int j = 0; j < 4; j++) *(u32x4*)(d + 4 * j) = *(u32x4*)(pk + 4 * j);
    } else {
      const u16* ap = (const u16*)Av + (size_t)(m0 + sr) * 1024 + k0 + seg;
#pragma unroll
      for (int j = 0; j < 4; j++)
        *(bf16x8*)&As[sr][seg + 8 * j] = *(const bf16x8*)(ap + 8 * j);
    }
    {
      const u16* bp = Bt + (size_t)(n0 + sr) * 1024 + k0 + seg;
#pragma unroll
      for (int j = 0; j < 4; j++)
        *(bf16x8*)&Bs[sr][seg + 8 * j] = *(const bf16x8*)(bp + 8 * j);
    }
    __syncthreads();
#pragma unroll
    for (int kk = 0; kk < 64; kk += 32) {
      bf16x8 af[4], bfr[4];
#pragma unroll
      for (int rt = 0; rt < 4; rt++)
        af[rt] = *(const bf16x8*)&As[wr + 16 * rt + ln][kk + quad * 8];
#pragma unroll
      for (int ct = 0; ct < 4; ct++)
        bfr[ct] = *(const bf16x8*)&Bs[wc + 16 * ct + ln][kk + quad * 8];
#pragma unroll
      for (int rt = 0; rt < 4; rt++)
#pragma unroll
        for (int ct = 0; ct < 4; ct++)
          acc[rt][ct] = mfma16(af[rt], bfr[ct], acc[rt][ct]);
    }
    __syncthreads();
  }

#pragma unroll
  for (int ct = 0; ct < 4; ct++) {
    int n = n0 + wc + 16 * ct + ln;
    float bs = bscale * bias[n];
#pragma unroll
    for (int rt = 0; rt < 4; rt++) {
#pragma unroll
      for (int r = 0; r < 4; r++) {
        int m = m0 + wr + 16 * rt + quad * 4 + r;
        float v = acc[rt][ct][r] + bs;
        if (layout == 0) {
          ((float*)Cv)[(size_t)m * 1024 + n] = v;
        } else {
          int b_ = m >> 10, s = m & 1023, h = n >> 6, d = n & 63;
          size_t idx = (layout == 1)
              ? ((size_t)(b_ * 16 + h) * 1024 + s) * 64 + d
              : ((size_t)(b_ * 16 + h) * 64 + d) * 1024 + s;
          ((u16*)Cv)[idx] = f2b(v);
        }
      }
    }
  }
}

// f32-A variant (R8 fallback path)
__global__ __launch_bounds__(256) void gemm_qkv_f32(
    const float* q, const float* k, const float* v, const u16* WT,
    const float* bq, const float* bk, const float* bv,
    u16* Qp, u16* Kp, u16* Vt) {
  int z = blockIdx.z;
  const void* A = (z == 0) ? (const void*)q : (z == 1) ? (const void*)k : (const void*)v;
  const u16* Bt = WT + (size_t)z * (1024 * 1024);
  const float* bias = (z == 0) ? bq : (z == 1) ? bk : bv;
  float bscale = (z == 0) ? 0.125f : 1.0f;
  void* C = (z == 0) ? (void*)Qp : (z == 1) ? (void*)Kp : (void*)Vt;
  gemm128_body<true>(A, Bt, bias, bscale, C, (z == 2) ? 2 : 1);
}

// bf16-A variant (fast path: q/k/v pre-converted)
__global__ __launch_bounds__(256) void gemm_qkv_bf(
    const u16* qb, const u16* kb, const u16* vb, const u16* WT,
    const float* bq, const float* bk, const float* bv,
    u16* Qp, u16* Kp, u16* Vt) {
  int z = blockIdx.z;
  const void* A = (z == 0) ? (const void*)qb : (z == 1) ? (const void*)kb : (const void*)vb;
  const u16* Bt = WT + (size_t)z * (1024 * 1024);
  const float* bias = (z == 0) ? bq : (z == 1) ? bk : bv;
  float bscale = (z == 0) ? 0.125f : 1.0f;
  void* C = (z == 0) ? (void*)Qp : (z == 1) ? (void*)Kp : (void*)Vt;
  gemm128_body<false>(A, Bt, bias, bscale, C, (z == 2) ? 2 : 1);
}

__global__ __launch_bounds__(256) void gemm_out(
    const u16* A, const u16* Bt, const float* bias, float* C) {
  gemm128_body<false>(A, Bt, bias, 1.0f, C, 0);
}

// ---- flash causal attention, 256-k super-iterations (unchanged from R8) ----
#define BSTRIDE 332   // u16 row stride
#define PSTRIDE 280   // u16 row stride; rows 16B-aligned for ds_read_b128

__global__ __launch_bounds__(256) void attn_v2(
    const u16* __restrict__ Q, const u16* __restrict__ K,
    const u16* __restrict__ Vt, const u16* __restrict__ RB,
    u16* __restrict__ att) {
  __shared__ __align__(16) u16 lPR[64 * BSTRIDE];  // rel band, 320 slots used
  __shared__ __align__(16) u16 lP[64 * PSTRIDE];   // P tile, 256 cols used

  int bh = blockIdx.x;
  int qt = 15 - blockIdx.y;                        // heavy tiles first
  int b = bh >> 4, h = bh & 15;
  int tid = threadIdx.x;
  int w = tid >> 6, lane = tid & 63, quad = lane >> 4, ln = lane & 15;

  const u16* Qb = Q + (size_t)bh * 65536;
  const u16* Kb = K + (size_t)bh * 65536;
  const u16* Vb = Vt + (size_t)bh * 65536;
  const u16* Rb = RB + h * 64;                     // row stride 1024

  int row0 = 16 * w + quad * 4;                    // C-layout row base
  int i0 = qt * 64;
  int R0f = 960 - i0;

  int qrow = i0 + 16 * w + ln;
  bf16x8 qa0 = *(const bf16x8*)(Qb + (size_t)qrow * 64 + quad * 8);
  bf16x8 qa1 = *(const bf16x8*)(Qb + (size_t)qrow * 64 + 32 + quad * 8);

  bf16x8 ones;
#pragma unroll
  for (int i = 0; i < 8; i++) ones[i] = (short)0x3F80;  // bf16 1.0

  f32x4 o[4], lacc;
#pragma unroll
  for (int c = 0; c < 4; c++) { o[c][0]=0.f; o[c][1]=0.f; o[c][2]=0.f; o[c][3]=0.f; }
  lacc[0]=0.f; lacc[1]=0.f; lacc[2]=0.f; lacc[3]=0.f;

#pragma unroll 1
  for (int js = 0; js <= i0; js += 256) {
    int ntiles = ((i0 - js) >> 6) + 1;
    if (ntiles > 4) ntiles = 4;
    int base = R0f + js;

    // ---- rel band: rows [base, base + 64*(ntiles+1)) ----
    int G = 4 * (ntiles + 1);
#pragma unroll 1
    for (int g = 0; g < G; g++) {
      int rrow = base + 16 * g + ln;
      int rl = rrow > 1023 ? 1023 : rrow;          // OOB rows only hit masked cols
      const u16* Rrow = Rb + (size_t)rl * 1024 + quad * 8;
      f32x4 a; a[0]=0.f; a[1]=0.f; a[2]=0.f; a[3]=0.f;
      a = mfma16(qa0, *(const bf16x8*)(Rrow), a);
      a = mfma16(qa1, *(const bf16x8*)(Rrow + 32), a);
#pragma unroll
      for (int r = 0; r < 4; r++)
        lPR[(row0 + r) * BSTRIDE + 16 * g + ln] = f2b(a[r]);
    }
    asm volatile("s_waitcnt lgkmcnt(0)" ::: "memory");  // band visible

    // ---- 4 independent score-tile chains ----
#pragma unroll
    for (int t = 0; t < 4; t++) {
      if (t < ntiles) {
        int j0 = js + 64 * t;
        bf16x8 kf[4][2];
#pragma unroll
        for (int c = 0; c < 4; c++) {
          const u16* Krow = Kb + (size_t)(j0 + 16 * c + ln) * 64 + quad * 8;
          kf[c][0] = *(const bf16x8*)(Krow);
          kf[c][1] = *(const bf16x8*)(Krow + 32);
        }
        f32x4 sc[4];
#pragma unroll
        for (int c = 0; c < 4; c++) {
          f32x4 a; a[0]=0.f; a[1]=0.f; a[2]=0.f; a[3]=0.f;
          a = mfma16(qa0, kf[c][0], a);
          a = mfma16(qa1, kf[c][1], a);
          sc[c] = a;
        }
        bool diag = (j0 == i0);
        int cbs = 64 * t + 63;                     // band slot = cbs - ii + jj
#pragma unroll
        for (int r = 0; r < 4; r++) {
          int ii = row0 + r;
#pragma unroll
          for (int c = 0; c < 4; c++) {
            int jj = 16 * c + ln;
            float s = sc[c][r] + b2f(lPR[ii * BSTRIDE + cbs - ii + jj]);
            float p = (diag && jj > ii) ? 0.f : __expf(s);
            lP[ii * PSTRIDE + 64 * t + 16 * c + ln] = f2b(p);
          }
        }
      }
    }
    asm volatile("s_waitcnt lgkmcnt(0)" ::: "memory");  // P visible

    // ---- PV GEMM over 256 k (+ row sums via ones-B MFMA) ----
    int KC = 2 * ntiles;
#pragma unroll 1
    for (int kc = 0; kc < KC; kc++) {
      bf16x8 pa = *(const bf16x8*)&lP[(16 * w + ln) * PSTRIDE + 32 * kc + quad * 8];
      lacc = mfma16(pa, ones, lacc);
#pragma unroll
      for (int c = 0; c < 4; c++) {
        const u16* Vrow = Vb + (size_t)(16 * c + ln) * 1024 + js + 32 * kc + quad * 8;
        o[c] = mfma16(pa, *(const bf16x8*)(Vrow), o[c]);
      }
    }
    asm volatile("s_waitcnt lgkmcnt(0)" ::: "memory");  // WAR: reads done
  }

  // ---- epilogue: normalize, merge heads ----
#pragma unroll
  for (int c = 0; c < 4; c++) {
#pragma unroll
    for (int r = 0; r < 4; r++) {
      int i_abs = i0 + row0 + r;
      att[((size_t)(b * 1024 + i_abs)) * 1024 + h * 64 + 16 * c + ln] =
          f2b(o[c][r] / lacc[r]);
    }
  }
}

// ---------------------------------------------------------------------------
extern "C" void kernel_launch(void* const* d_in, const int* in_sizes, int n_in,
                              void* d_out, int out_size, void* d_ws, size_t ws_size,
                              hipStream_t stream) {
  const float* query = (const float*)d_in[0];
  const float* key   = (const float*)d_in[1];
  const float* value = (const float*)d_in[2];
  // d_in[3] = attention_mask (int32, triu k=1) -- causal, hardcoded in attn
  const float* Wq = (const float*)d_in[4];
  const float* bq = (const float*)d_in[5];
  const float* Wk = (const float*)d_in[6];
  const float* bk = (const float*)d_in[7];
  const float* Wv = (const float*)d_in[8];
  const float* bv = (const float*)d_in[9];
  const float* RT = (const float*)d_in[10];
  const float* Wo = (const float*)d_in[11];
  const float* bo = (const float*)d_in[12];
  float* out = (float*)d_out;

  const size_t EM = 1024 * 1024;     // elems of one 1024x1024 matrix
  u16* ws   = (u16*)d_ws;
  u16* WT   = ws;                    // [0,3EM): WqT, WkT, WvT
  u16* relb = ws + 3 * EM;           // [3EM,4EM)
  u16* Kp   = ws + 4 * EM;           // [4EM,8EM)
  u16* Vtp  = ws + 8 * EM;           // [8EM,12EM)
  u16* Qp   = (u16*)d_out;           // d_out scratch, front half
  u16* attb = (u16*)d_out + 4 * EM;  // d_out scratch, back half
  u16* attc = ws + 4 * EM;           // att copy over dead Kp
  u16* WoT  = ws;                    // over dead WT

  prep<<<dim3(16, 16, 4), 256, 0, stream>>>(Wq, Wk, Wv, RT,
                                            WT, WT + EM, WT + 2 * EM, relb);

  if (ws_size >= (size_t)48 * 1024 * 1024) {
    // fast path: pre-convert q/k/v to bf16, GEMM stages bf16 A
    u16* qb = ws + 12 * EM;          // [12EM,16EM)
    u16* kb = ws + 16 * EM;          // [16EM,20EM)
    u16* vb = ws + 20 * EM;          // [20EM,24EM)
    cvt_qkv<<<dim3(4096, 3), 256, 0, stream>>>(query, key, value, qb, kb, vb);
    gemm_qkv_bf<<<dim3(32, 8, 3), 256, 0, stream>>>(qb, kb, vb, WT,
                                                    bq, bk, bv, Qp, Kp, Vtp);
  } else {
    gemm_qkv_f32<<<dim3(32, 8, 3), 256, 0, stream>>>(query, key, value, WT,
                                                     bq, bk, bv, Qp, Kp, Vtp);
  }

  attn_v2<<<dim3(64, 16), 256, 0, stream>>>(Qp, Kp, Vtp, relb, attb);
  hipMemcpyAsync(attc, attb, 8 * 1024 * 1024, hipMemcpyDeviceToDevice, stream);
  transpose_wo<<<dim3(16, 16), 256, 0, stream>>>(Wo, WoT);
  gemm_out<<<dim3(32, 8), 256, 0, stream>>>(attc, WoT, bo, out);
}